// Round 4
// baseline (53.144 us; speedup 1.0000x reference)
//
#include <hip/hip_runtime.h>

// x: (2,2,128,256,256) fp32 NMS-3D. Strict 26-neighbor max, interior only.
// One wave = one full w-row (64 lanes x float4). Rolls along d keeping
// reduced plane state in registers: per d-step load only 3 rows of plane d+1.
// R4: WAVES=16 (halve h-halo, 16KiB contiguous stores/plane), CH=16,
//     XCD-chunked swizzle, non-temporal stores.

#define W 256
#define H 256
#define D 128
#define PLANE (H * W)     // 65536
#define VOL (D * PLANE)   // 8388608
#define CH 16             // d-chunk per block
#define WAVES 16          // h-rows per block (1024 threads)
#define NXCD 8

typedef float v4f __attribute__((ext_vector_type(4)));

__device__ __forceinline__ float max3f(float a, float b, float c) {
    return fmaxf(fmaxf(a, b), c);
}

struct PState {
    float pm[4];  // full 3x3 plane max per output j
    float pc[4];  // plane max excluding center (for the center plane) per j
    float c[4];   // center row values
};

__device__ __forceinline__ void plane_state(const float* __restrict__ base, PState& s) {
    float4 t = *reinterpret_cast<const float4*>(base - W);
    float4 m = *reinterpret_cast<const float4*>(base);
    float4 b = *reinterpret_cast<const float4*>(base + W);
    // neighbors across lanes: w0-1 = lane-1's .w, w0+4 = lane+1's .x
    float tl = __shfl_up(t.w, 1), tr = __shfl_down(t.x, 1);
    float ml = __shfl_up(m.w, 1), mr = __shfl_down(m.x, 1);
    float bl = __shfl_up(b.w, 1), br = __shfl_down(b.x, 1);

    float rt[4], rb[4], rm[4], nc[4];
    rt[0] = max3f(tl, t.x, t.y); rt[1] = max3f(t.x, t.y, t.z);
    rt[2] = max3f(t.y, t.z, t.w); rt[3] = max3f(t.z, t.w, tr);
    rb[0] = max3f(bl, b.x, b.y); rb[1] = max3f(b.x, b.y, b.z);
    rb[2] = max3f(b.y, b.z, b.w); rb[3] = max3f(b.z, b.w, br);
    rm[0] = max3f(ml, m.x, m.y); rm[1] = max3f(m.x, m.y, m.z);
    rm[2] = max3f(m.y, m.z, m.w); rm[3] = max3f(m.z, m.w, mr);
    nc[0] = fmaxf(ml, m.y); nc[1] = fmaxf(m.x, m.z);
    nc[2] = fmaxf(m.y, m.w); nc[3] = fmaxf(m.z, mr);

    s.c[0] = m.x; s.c[1] = m.y; s.c[2] = m.z; s.c[3] = m.w;
    #pragma unroll
    for (int j = 0; j < 4; ++j) {
        s.pm[j] = max3f(rt[j], rm[j], rb[j]);
        s.pc[j] = max3f(rt[j], nc[j], rb[j]);
    }
}

__device__ __forceinline__ void nt_store4(float* p, float a, float b, float c, float d) {
    v4f v = {a, b, c, d};
    __builtin_nontemporal_store(v, reinterpret_cast<v4f*>(p));
}

__global__ __launch_bounds__(WAVES * 64) void nms3d_kernel(const float* __restrict__ x,
                                                           float* __restrict__ out) {
    const int lane = threadIdx.x & 63;
    const int wv = threadIdx.x >> 6;
    const int HG = H / WAVES;                 // 16 h-groups
    const int NWG = (D / CH) * 4 * HG;        // 512 blocks
    const int CPX = NWG / NXCD;               // 64 blocks per XCD

    // XCD-chunked swizzle: hardware round-robins blockIdx across XCDs;
    // remap so each XCD owns a contiguous logical range (h-halo L2 sharing).
    const int lb = (blockIdx.x % NXCD) * CPX + blockIdx.x / NXCD;

    const int hgroup = lb % HG;
    const int bc = (lb / HG) & 3;
    const int dchunk = lb / (HG * 4);
    const int h = hgroup * WAVES + wv;
    const int w0 = lane * 4;
    const int dlo = dchunk * CH;
    const int dhi = dlo + CH;
    const int rowoff = bc * VOL + h * W + w0;

    // boundary h rows: all zeros for this chunk's d range
    if (h == 0 || h == H - 1) {
        for (int d = dlo; d < dhi; ++d)
            nt_store4(out + rowoff + d * PLANE, 0.f, 0.f, 0.f, 0.f);
        return;
    }

    if (dlo == 0)
        nt_store4(out + rowoff, 0.f, 0.f, 0.f, 0.f);                      // d = 0
    if (dhi == D)
        nt_store4(out + rowoff + (D - 1) * PLANE, 0.f, 0.f, 0.f, 0.f);    // d = 127

    const int dstart = (dlo == 0) ? 1 : dlo;
    const int dend = (dhi == D) ? D - 1 : dhi;

    // prime planes dstart-1 and dstart
    float pm0[4];        // plane d-1: only full plane-max needed
    PState s1;           // plane d (center candidate)
    {
        PState tmp;
        plane_state(x + rowoff + (dstart - 1) * PLANE, tmp);
        #pragma unroll
        for (int j = 0; j < 4; ++j) pm0[j] = tmp.pm[j];
        plane_state(x + rowoff + dstart * PLANE, s1);
    }

    const bool vj0 = (lane != 0);    // w = 0 boundary
    const bool vj3 = (lane != 63);   // w = 255 boundary

    #pragma unroll 4
    for (int d = dstart; d < dend; ++d) {
        PState s2;
        plane_state(x + rowoff + (d + 1) * PLANE, s2);

        float nb0 = max3f(pm0[0], s1.pc[0], s2.pm[0]);
        float nb1 = max3f(pm0[1], s1.pc[1], s2.pm[1]);
        float nb2 = max3f(pm0[2], s1.pc[2], s2.pm[2]);
        float nb3 = max3f(pm0[3], s1.pc[3], s2.pm[3]);
        nt_store4(out + rowoff + d * PLANE,
                  (vj0 && s1.c[0] > nb0) ? s1.c[0] : 0.f,
                  (s1.c[1] > nb1) ? s1.c[1] : 0.f,
                  (s1.c[2] > nb2) ? s1.c[2] : 0.f,
                  (vj3 && s1.c[3] > nb3) ? s1.c[3] : 0.f);

        // rotate: d-1 <- d, d <- d+1
        #pragma unroll
        for (int j = 0; j < 4; ++j) {
            pm0[j] = s1.pm[j];
            s1.pm[j] = s2.pm[j];
            s1.pc[j] = s2.pc[j];
            s1.c[j] = s2.c[j];
        }
    }
}

extern "C" void kernel_launch(void* const* d_in, const int* in_sizes, int n_in,
                              void* d_out, int out_size, void* d_ws, size_t ws_size,
                              hipStream_t stream) {
    const float* x = (const float*)d_in[0];
    float* out = (float*)d_out;

    const int HG = H / WAVES;                         // 16
    const int blocks = (D / CH) * 4 * HG;             // 8 * 4 * 16 = 512
    hipLaunchKernelGGL(nms3d_kernel, dim3(blocks), dim3(WAVES * 64), 0, stream,
                       x, out);
}

// Round 5
// 46.549 us; speedup vs baseline: 1.1417x; 1.1417x over previous
//
#include <hip/hip_runtime.h>

// x: (2,2,128,256,256) fp32 NMS-3D. Strict 26-neighbor max, interior only.
// One wave = one full w-row (64 lanes x float4). Rolls along d keeping
// reduced plane state in registers: per d-step load only 3 rows of plane d+1.
// R5 = revert to R3 winner: WAVES=8 (512-thread blocks — smaller scheduling
// quantum beats halo halving; WAVES=16 regressed 46.6->53.1us), CH=16,
// XCD-chunked swizzle, non-temporal stores.

#define W 256
#define H 256
#define D 128
#define PLANE (H * W)     // 65536
#define VOL (D * PLANE)   // 8388608
#define CH 16             // d-chunk per block
#define WAVES 8           // h-rows per block
#define NXCD 8

typedef float v4f __attribute__((ext_vector_type(4)));

__device__ __forceinline__ float max3f(float a, float b, float c) {
    return fmaxf(fmaxf(a, b), c);
}

struct PState {
    float pm[4];  // full 3x3 plane max per output j
    float pc[4];  // plane max excluding center (for the center plane) per j
    float c[4];   // center row values
};

__device__ __forceinline__ void plane_state(const float* __restrict__ base, PState& s) {
    float4 t = *reinterpret_cast<const float4*>(base - W);
    float4 m = *reinterpret_cast<const float4*>(base);
    float4 b = *reinterpret_cast<const float4*>(base + W);
    // neighbors across lanes: w0-1 = lane-1's .w, w0+4 = lane+1's .x
    float tl = __shfl_up(t.w, 1), tr = __shfl_down(t.x, 1);
    float ml = __shfl_up(m.w, 1), mr = __shfl_down(m.x, 1);
    float bl = __shfl_up(b.w, 1), br = __shfl_down(b.x, 1);

    float rt[4], rb[4], rm[4], nc[4];
    rt[0] = max3f(tl, t.x, t.y); rt[1] = max3f(t.x, t.y, t.z);
    rt[2] = max3f(t.y, t.z, t.w); rt[3] = max3f(t.z, t.w, tr);
    rb[0] = max3f(bl, b.x, b.y); rb[1] = max3f(b.x, b.y, b.z);
    rb[2] = max3f(b.y, b.z, b.w); rb[3] = max3f(b.z, b.w, br);
    rm[0] = max3f(ml, m.x, m.y); rm[1] = max3f(m.x, m.y, m.z);
    rm[2] = max3f(m.y, m.z, m.w); rm[3] = max3f(m.z, m.w, mr);
    nc[0] = fmaxf(ml, m.y); nc[1] = fmaxf(m.x, m.z);
    nc[2] = fmaxf(m.y, m.w); nc[3] = fmaxf(m.z, mr);

    s.c[0] = m.x; s.c[1] = m.y; s.c[2] = m.z; s.c[3] = m.w;
    #pragma unroll
    for (int j = 0; j < 4; ++j) {
        s.pm[j] = max3f(rt[j], rm[j], rb[j]);
        s.pc[j] = max3f(rt[j], nc[j], rb[j]);
    }
}

__device__ __forceinline__ void nt_store4(float* p, float a, float b, float c, float d) {
    v4f v = {a, b, c, d};
    __builtin_nontemporal_store(v, reinterpret_cast<v4f*>(p));
}

__global__ __launch_bounds__(WAVES * 64) void nms3d_kernel(const float* __restrict__ x,
                                                           float* __restrict__ out) {
    const int lane = threadIdx.x & 63;
    const int wv = threadIdx.x >> 6;
    const int HG = H / WAVES;                 // 32 h-groups
    const int NWG = (D / CH) * 4 * HG;        // 1024 blocks
    const int CPX = NWG / NXCD;               // 128 blocks per XCD

    // XCD-chunked swizzle: hardware round-robins blockIdx across XCDs;
    // remap so each XCD owns a contiguous logical range (h-halo L2 sharing).
    const int lb = (blockIdx.x % NXCD) * CPX + blockIdx.x / NXCD;

    const int hgroup = lb % HG;
    const int bc = (lb / HG) & 3;
    const int dchunk = lb / (HG * 4);
    const int h = hgroup * WAVES + wv;
    const int w0 = lane * 4;
    const int dlo = dchunk * CH;
    const int dhi = dlo + CH;
    const int rowoff = bc * VOL + h * W + w0;

    // boundary h rows: all zeros for this chunk's d range
    if (h == 0 || h == H - 1) {
        for (int d = dlo; d < dhi; ++d)
            nt_store4(out + rowoff + d * PLANE, 0.f, 0.f, 0.f, 0.f);
        return;
    }

    if (dlo == 0)
        nt_store4(out + rowoff, 0.f, 0.f, 0.f, 0.f);                      // d = 0
    if (dhi == D)
        nt_store4(out + rowoff + (D - 1) * PLANE, 0.f, 0.f, 0.f, 0.f);    // d = 127

    const int dstart = (dlo == 0) ? 1 : dlo;
    const int dend = (dhi == D) ? D - 1 : dhi;

    // prime planes dstart-1 and dstart
    float pm0[4];        // plane d-1: only full plane-max needed
    PState s1;           // plane d (center candidate)
    {
        PState tmp;
        plane_state(x + rowoff + (dstart - 1) * PLANE, tmp);
        #pragma unroll
        for (int j = 0; j < 4; ++j) pm0[j] = tmp.pm[j];
        plane_state(x + rowoff + dstart * PLANE, s1);
    }

    const bool vj0 = (lane != 0);    // w = 0 boundary
    const bool vj3 = (lane != 63);   // w = 255 boundary

    #pragma unroll 4
    for (int d = dstart; d < dend; ++d) {
        PState s2;
        plane_state(x + rowoff + (d + 1) * PLANE, s2);

        float nb0 = max3f(pm0[0], s1.pc[0], s2.pm[0]);
        float nb1 = max3f(pm0[1], s1.pc[1], s2.pm[1]);
        float nb2 = max3f(pm0[2], s1.pc[2], s2.pm[2]);
        float nb3 = max3f(pm0[3], s1.pc[3], s2.pm[3]);
        nt_store4(out + rowoff + d * PLANE,
                  (vj0 && s1.c[0] > nb0) ? s1.c[0] : 0.f,
                  (s1.c[1] > nb1) ? s1.c[1] : 0.f,
                  (s1.c[2] > nb2) ? s1.c[2] : 0.f,
                  (vj3 && s1.c[3] > nb3) ? s1.c[3] : 0.f);

        // rotate: d-1 <- d, d <- d+1
        #pragma unroll
        for (int j = 0; j < 4; ++j) {
            pm0[j] = s1.pm[j];
            s1.pm[j] = s2.pm[j];
            s1.pc[j] = s2.pc[j];
            s1.c[j] = s2.c[j];
        }
    }
}

extern "C" void kernel_launch(void* const* d_in, const int* in_sizes, int n_in,
                              void* d_out, int out_size, void* d_ws, size_t ws_size,
                              hipStream_t stream) {
    const float* x = (const float*)d_in[0];
    float* out = (float*)d_out;

    const int HG = H / WAVES;                         // 32
    const int blocks = (D / CH) * 4 * HG;             // 8 * 4 * 32 = 1024
    hipLaunchKernelGGL(nms3d_kernel, dim3(blocks), dim3(WAVES * 64), 0, stream,
                       x, out);
}